// Round 2
// baseline (9299.549 us; speedup 1.0000x reference)
//
#include <hip/hip_runtime.h>
#include <cstdint>
#include <cstddef>

#define NTOT 25600
#define BB 64
#define MAXN 512
#define DD 256
#define HH 8
#define FF 1024
#define HK 2048
#define NR (NTOT + BB)   // real rows + 1 pad-representative per batch
#define EPS 1e-3f

typedef unsigned short u16;
typedef unsigned int   u32;

__device__ __forceinline__ float bf2f(u16 u) { return __uint_as_float(((u32)u) << 16); }
__device__ __forceinline__ u16 f2bf(float f) {
    u32 x = __float_as_uint(f);
    return (u16)((x + 0x7fffu + ((x >> 16) & 1u)) >> 16);  // RNE; inputs finite
}

// ---------------- K1: segment starts via binary search (indicator sorted) ----
__global__ void k_starts(const int* __restrict__ ind, int* __restrict__ starts) {
    int b = threadIdx.x;
    if (b > BB) return;
    int lo = 0, hi = NTOT;
    while (lo < hi) { int mid = (lo + hi) >> 1; if (ind[mid] < b) lo = mid + 1; else hi = mid; }
    starts[b] = lo;   // starts[64] == NTOT
}

// ---------------- K2: acc = x + bo (pad-rep rows: bo only) -------------------
__global__ __launch_bounds__(256) void k_init_acc(
    const float* __restrict__ x, const float* __restrict__ bo, float* __restrict__ acc) {
    int row = blockIdx.x, t = threadIdx.x;
    float v = bo[t];
    if (row < NTOT) v += x[(size_t)row * DD + t];
    acc[(size_t)row * DD + t] = v;
}

// ---------------- K3: QKV projection for head group [h0, h0+G) --------------
// out[row, G*256] bf16; z selects q/k/v. Pad rows (>= NTOT): x=0 -> bias only.
__global__ __launch_bounds__(256) void k_qkv(
    const float* __restrict__ x,
    const float* __restrict__ Wq, const float* __restrict__ Wk, const float* __restrict__ Wv,
    const float* __restrict__ bq, const float* __restrict__ bk, const float* __restrict__ bv,
    u16* __restrict__ q, u16* __restrict__ k, u16* __restrict__ v, int G, int h0)
{
    int z = blockIdx.z;
    const float* W    = (z == 0) ? Wq : ((z == 1) ? Wk : Wv);
    const float* bias = (z == 0) ? bq : ((z == 1) ? bk : bv);
    u16* out          = (z == 0) ? q  : ((z == 1) ? k  : v);
    int S = G << 8;                       // row stride (elements)
    int row0 = blockIdx.x * 64;
    int col0 = blockIdx.y * 64;           // local col in [0, S)
    int gc0  = (h0 << 8) + col0;          // global col in [0, 2048)
    int t = threadIdx.x;
    __shared__ __align__(16) float Asub[16][68];
    __shared__ __align__(16) float Bsub[16][68];
    int rm = t & 15, cn = t >> 4;
    float acc[4][4];
#pragma unroll
    for (int i = 0; i < 4; ++i)
#pragma unroll
        for (int j = 0; j < 4; ++j) acc[i][j] = 0.f;

    for (int k0 = 0; k0 < DD; k0 += 16) {
        {   // A tile: 64 rows x 16 k
            int r = t >> 2, kk0 = (t & 3) * 4;
            int row = row0 + r;
            float4 a4 = make_float4(0.f, 0.f, 0.f, 0.f);
            if (row < NTOT) a4 = *reinterpret_cast<const float4*>(&x[(size_t)row * DD + k0 + kk0]);
            Asub[kk0 + 0][r] = a4.x; Asub[kk0 + 1][r] = a4.y;
            Asub[kk0 + 2][r] = a4.z; Asub[kk0 + 3][r] = a4.w;
        }
        {   // B tile: 16 k x 64 cols
            int kk = t >> 4, c0 = (t & 15) * 4;
            float4 b4 = *reinterpret_cast<const float4*>(&W[(size_t)(k0 + kk) * HK + gc0 + c0]);
            *reinterpret_cast<float4*>(&Bsub[kk][c0]) = b4;
        }
        __syncthreads();
#pragma unroll
        for (int kk = 0; kk < 16; ++kk) {
            const float4 a4 = *reinterpret_cast<const float4*>(&Asub[kk][rm * 4]);
            const float4 b4 = *reinterpret_cast<const float4*>(&Bsub[kk][cn * 4]);
            const float av[4] = {a4.x, a4.y, a4.z, a4.w};
            const float bw[4] = {b4.x, b4.y, b4.z, b4.w};
#pragma unroll
            for (int i = 0; i < 4; ++i)
#pragma unroll
                for (int j = 0; j < 4; ++j) acc[i][j] += av[i] * bw[j];
        }
        __syncthreads();
    }
#pragma unroll
    for (int i = 0; i < 4; ++i) {
        int row = row0 + rm * 4 + i;
        u16 tmp[4];
#pragma unroll
        for (int j = 0; j < 4; ++j) tmp[j] = f2bf(acc[i][j] + bias[gc0 + cn * 4 + j]);
        ushort4 st; st.x = tmp[0]; st.y = tmp[1]; st.z = tmp[2]; st.w = tmp[3];
        *reinterpret_cast<ushort4*>(&out[(size_t)row * S + col0 + cn * 4]) = st;
    }
}

// ---------------- K4: attention per (b, h in group). o may alias q (safe:
// q rows of a q-block are staged to LDS before their o rows are written,
// and blocks touch disjoint row-range x head-slice).
__global__ __launch_bounds__(256) void k_attn(
    const u16* __restrict__ q, const u16* __restrict__ kb, const u16* __restrict__ vb,
    u16* __restrict__ o, const int* __restrict__ starts, int G, int QS)
{
    int b = blockIdx.x / G;
    int h = blockIdx.x % G;
    int S = G << 8;
    int t = threadIdx.x;
    int lane = t & 63, wid = t >> 6;
    int start = starts[b];
    int N = starts[b + 1] - start;
    if (N > MAXN) N = MAXN;
    int R = N + 1;
    __shared__ __align__(16) float q_lds[8][261];   // stride 261 -> conflict-free dots
    __shared__ __align__(16) float k_lds[32][261];
    __shared__ float p[8][512];
    __shared__ float red4[4];
    __shared__ float ssum[8];
    size_t hoff = (size_t)h << 8;

    if (N == 0) {   // all rows pad: softmax uniform over identical rows -> o = v_pad
        if (blockIdx.y == 0) {
            int g = NTOT + b;
            o[(size_t)g * S + hoff + t] = vb[(size_t)g * S + hoff + t];
        }
        return;
    }

    int nqb = (R + 7) >> 3;
    for (int qb = blockIdx.y; qb < nqb; qb += QS) {
        {   // load 8 q rows (bf16x8 per thread)
            int qr = t >> 5, f0 = (t & 31) * 8;
            int qi = qb * 8 + qr;
            float vals[8];
            if (qi < R) {
                int g = (qi < N) ? (start + qi) : (NTOT + b);
                uint4 raw = *reinterpret_cast<const uint4*>(&q[(size_t)g * S + hoff + f0]);
                u32 wrd[4] = {raw.x, raw.y, raw.z, raw.w};
#pragma unroll
                for (int e = 0; e < 4; ++e) {
                    vals[2 * e]     = bf2f((u16)(wrd[e] & 0xffffu));
                    vals[2 * e + 1] = bf2f((u16)(wrd[e] >> 16));
                }
            } else {
#pragma unroll
                for (int e = 0; e < 8; ++e) vals[e] = 0.f;
            }
#pragma unroll
            for (int e = 0; e < 8; ++e) q_lds[qr][f0 + e] = vals[e];
        }
        __syncthreads();

        int nkt = (N + 31) >> 5;
        for (int kt = 0; kt < nkt; ++kt) {
            {   // stage 32-key tile
                int kr = t >> 3, f0 = (t & 7) * 32;
                int ml = kt * 32 + kr;
                if (ml < N) {
                    int g = start + ml;
#pragma unroll
                    for (int it = 0; it < 4; ++it) {
                        int f = f0 + it * 8;
                        uint4 raw = *reinterpret_cast<const uint4*>(&kb[(size_t)g * S + hoff + f]);
                        u32 wrd[4] = {raw.x, raw.y, raw.z, raw.w};
#pragma unroll
                        for (int e = 0; e < 4; ++e) {
                            k_lds[kr][f + 2 * e]     = bf2f((u16)(wrd[e] & 0xffffu));
                            k_lds[kr][f + 2 * e + 1] = bf2f((u16)(wrd[e] >> 16));
                        }
                    }
                }
            }
            __syncthreads();
            {   // scores
                int qr = t >> 5, kk = t & 31;
                int m = kt * 32 + kk;
                if (m < N) {
                    float acc = 0.f;
#pragma unroll 8
                    for (int j = 0; j < 256; ++j) acc += q_lds[qr][j] * k_lds[kk][j];
                    p[qr][m] = acc * 0.0625f;   // 1/sqrt(256)
                }
            }
            __syncthreads();
        }

        // softmax per q-row (unnormalized; normalize at PV write)
        for (int qr = 0; qr < 8; ++qr) {
            int qi = qb * 8 + qr;
            bool valid = (qi < R);
            float lm = -1e30f;
            if (valid) for (int m = t; m < N; m += 256) lm = fmaxf(lm, p[qr][m]);
#pragma unroll
            for (int off = 32; off > 0; off >>= 1) lm = fmaxf(lm, __shfl_xor(lm, off, 64));
            if (lane == 0) red4[wid] = lm;
            __syncthreads();
            float mx = fmaxf(fmaxf(red4[0], red4[1]), fmaxf(red4[2], red4[3]));
            __syncthreads();
            float ls = 0.f;
            if (valid) for (int m = t; m < N; m += 256) {
                float e = __expf(p[qr][m] - mx);
                p[qr][m] = e;
                ls += e;
            }
#pragma unroll
            for (int off = 32; off > 0; off >>= 1) ls += __shfl_xor(ls, off, 64);
            if (lane == 0) red4[wid] = ls;
            __syncthreads();
            if (t == 0) ssum[qr] = red4[0] + red4[1] + red4[2] + red4[3];
            __syncthreads();
        }

        {   // PV: thread = feature
            float acc8[8];
#pragma unroll
            for (int i = 0; i < 8; ++i) acc8[i] = 0.f;
            for (int m = 0; m < N; ++m) {
                float vv = bf2f(vb[(size_t)(start + m) * S + hoff + t]);
#pragma unroll
                for (int qr = 0; qr < 8; ++qr) acc8[qr] += p[qr][m] * vv;
            }
#pragma unroll
            for (int qr = 0; qr < 8; ++qr) {
                int qi = qb * 8 + qr;
                if (qi < R) {
                    int g = (qi < N) ? (start + qi) : (NTOT + b);
                    o[(size_t)g * S + hoff + t] = f2bf(acc8[qr] / ssum[qr]);
                }
            }
        }
        __syncthreads();
    }
}

// ---------------- K5: acc += o[NR, G*256] @ Wo[h0*256 : h0*256+G*256, 256] ---
__global__ __launch_bounds__(256) void k_proj(
    const u16* __restrict__ o, const float* __restrict__ Wo,
    float* __restrict__ acc, int G, int h0)
{
    int S = G << 8;                      // K extent this pass
    int g0 = blockIdx.x * 16;
    int t = threadIdx.x;
    __shared__ float A_lds[32][17];
    __shared__ __align__(16) float B_lds[32][260];
    int rm = t >> 6;                     // 4 row groups x 4 rows
    int cn = t & 63;                     // 64 col groups x 4 cols
    float av[4][4];
#pragma unroll
    for (int i = 0; i < 4; ++i)
#pragma unroll
        for (int j = 0; j < 4; ++j) av[i][j] = 0.f;

    for (int k0 = 0; k0 < S; k0 += 32) {
        {   // A: o bf16 [16 rows][32 k]
            int r = t >> 4, kk0 = (t & 15) * 2;
            u32 raw = *reinterpret_cast<const u32*>(&o[(size_t)(g0 + r) * S + k0 + kk0]);
            A_lds[kk0][r]     = bf2f((u16)(raw & 0xffffu));
            A_lds[kk0 + 1][r] = bf2f((u16)(raw >> 16));
        }
        {   // B: Wo [32 k][256 cols], global row = h0*256 + k0 + kk
            int kk = t >> 3, c0 = (t & 7) * 32;
#pragma unroll
            for (int it = 0; it < 8; ++it) {
                int c = c0 + it * 4;
                *reinterpret_cast<float4*>(&B_lds[kk][c]) =
                    *reinterpret_cast<const float4*>(&Wo[(size_t)((h0 << 8) + k0 + kk) * DD + c]);
            }
        }
        __syncthreads();
#pragma unroll
        for (int kk = 0; kk < 32; ++kk) {
            float a0 = A_lds[kk][rm * 4 + 0], a1 = A_lds[kk][rm * 4 + 1];
            float a2 = A_lds[kk][rm * 4 + 2], a3 = A_lds[kk][rm * 4 + 3];
            const float4 b4 = *reinterpret_cast<const float4*>(&B_lds[kk][cn * 4]);
            av[0][0] += a0 * b4.x; av[0][1] += a0 * b4.y; av[0][2] += a0 * b4.z; av[0][3] += a0 * b4.w;
            av[1][0] += a1 * b4.x; av[1][1] += a1 * b4.y; av[1][2] += a1 * b4.z; av[1][3] += a1 * b4.w;
            av[2][0] += a2 * b4.x; av[2][1] += a2 * b4.y; av[2][2] += a2 * b4.z; av[2][3] += a2 * b4.w;
            av[3][0] += a3 * b4.x; av[3][1] += a3 * b4.y; av[3][2] += a3 * b4.z; av[3][3] += a3 * b4.w;
        }
        __syncthreads();
    }
#pragma unroll
    for (int i = 0; i < 4; ++i) {
        int grow = g0 + rm * 4 + i;
#pragma unroll
        for (int j = 0; j < 4; ++j) {
            int c = cn * 4 + j;
            acc[(size_t)grow * DD + c] += av[i][j];   // one owner per element -> deterministic
        }
    }
}

// ---------------- K6: hbuf = LN1(acc) ---------------------------------------
__global__ __launch_bounds__(256) void k_ln1(
    const float* __restrict__ acc, const float* __restrict__ g1, const float* __restrict__ be1,
    float* __restrict__ hbuf)
{
    int w = threadIdx.x >> 6, lane = threadIdx.x & 63;
    int row = blockIdx.x * 4 + w;
    const float* a = &acc[(size_t)row * DD];
    float v0 = a[lane], v1 = a[lane + 64], v2 = a[lane + 128], v3 = a[lane + 192];
    float s  = v0 + v1 + v2 + v3;
    float ss = v0 * v0 + v1 * v1 + v2 * v2 + v3 * v3;
#pragma unroll
    for (int off = 32; off > 0; off >>= 1) { s += __shfl_xor(s, off, 64); ss += __shfl_xor(ss, off, 64); }
    float mean = s * (1.f / 256.f);
    float var  = ss * (1.f / 256.f) - mean * mean;
    float rstd = rsqrtf(var + EPS);
    float* hb = &hbuf[(size_t)row * DD];
    hb[lane]       = (v0 - mean) * rstd * g1[lane]       + be1[lane];
    hb[lane + 64]  = (v1 - mean) * rstd * g1[lane + 64]  + be1[lane + 64];
    hb[lane + 128] = (v2 - mean) * rstd * g1[lane + 128] + be1[lane + 128];
    hb[lane + 192] = (v3 - mean) * rstd * g1[lane + 192] + be1[lane + 192];
}

// ---------------- K7: FFN (F-chunked, fused) + residual + LN2 -> rowout -----
__global__ __launch_bounds__(256) void k_ffn(
    const float* __restrict__ hbuf, const float* __restrict__ W1, const float* __restrict__ b1,
    const float* __restrict__ W2, const float* __restrict__ b2,
    const float* __restrict__ g2, const float* __restrict__ be2,
    float* __restrict__ rowout)
{
    int g0 = blockIdx.x * 16;
    int t = threadIdx.x;
    int lane = t & 63, w = t >> 6;
    __shared__ __align__(16) float h_lds[16][264];
    __shared__ float mid[16][132];
    __shared__ float rowvals[16][264];
    {   // load 16 h rows
        int r = t >> 4, c0 = (t & 15) * 16;
#pragma unroll
        for (int it = 0; it < 4; ++it) {
            int c = c0 + it * 4;
            *reinterpret_cast<float4*>(&h_lds[r][c]) =
                *reinterpret_cast<const float4*>(&hbuf[(size_t)(g0 + r) * DD + c]);
        }
    }
    __syncthreads();
    float acc2[16];
#pragma unroll
    for (int i = 0; i < 16; ++i) acc2[i] = 0.f;
    int j  = t & 127;
    int rg = t >> 7;
    int d  = t;
    for (int fc = 0; fc < FF; fc += 128) {
        float acc1[8];
#pragma unroll
        for (int i = 0; i < 8; ++i) acc1[i] = 0.f;
        for (int kk = 0; kk < DD; ++kk) {
            float w1v = W1[(size_t)kk * FF + fc + j];
#pragma unroll
            for (int rr = 0; rr < 8; ++rr) acc1[rr] += h_lds[rg * 8 + rr][kk] * w1v;
        }
#pragma unroll
        for (int rr = 0; rr < 8; ++rr) mid[rg * 8 + rr][j] = fmaxf(acc1[rr] + b1[fc + j], 0.f);
        __syncthreads();
        for (int kk2 = 0; kk2 < 128; ++kk2) {
            float w2v = W2[(size_t)(fc + kk2) * DD + d];
#pragma unroll
            for (int r = 0; r < 16; ++r) acc2[r] += mid[r][kk2] * w2v;
        }
        __syncthreads();
    }
#pragma unroll
    for (int r = 0; r < 16; ++r) rowvals[r][d] = acc2[r] + b2[d] + h_lds[r][d];
    __syncthreads();
    for (int rr = 0; rr < 4; ++rr) {
        int r = w * 4 + rr; int grow = g0 + r;
        float s = 0.f, ss = 0.f;
#pragma unroll
        for (int jj = 0; jj < 4; ++jj) { float vv = rowvals[r][lane + jj * 64]; s += vv; ss += vv * vv; }
#pragma unroll
        for (int off = 32; off > 0; off >>= 1) { s += __shfl_xor(s, off, 64); ss += __shfl_xor(ss, off, 64); }
        float mean = s * (1.f / 256.f);
        float var  = ss * (1.f / 256.f) - mean * mean;
        float rstd = rsqrtf(var + EPS);
#pragma unroll
        for (int jj = 0; jj < 4; ++jj) {
            int c = lane + jj * 64;
            rowout[(size_t)grow * DD + c] = (rowvals[r][c] - mean) * rstd * g2[c] + be2[c];
        }
    }
}

// ---------------- K8: pooled readout ----------------------------------------
__global__ void k_pool(const float* __restrict__ rowout, const int* __restrict__ starts,
                       float* __restrict__ out)
{
    int b = blockIdx.x; int d = threadIdx.x;
    int start = starts[b];
    int N = starts[b + 1] - start;
    if (N > MAXN) N = MAXN;
    float s = 0.f;
    for (int n = 0; n < N; ++n) s += rowout[(size_t)(start + n) * DD + d];
    s += (float)(MAXN - N) * rowout[(size_t)(NTOT + b) * DD + d];
    out[(size_t)b * DD + d] = s * (1.f / 512.f);
}

extern "C" void kernel_launch(void* const* d_in, const int* in_sizes, int n_in,
                              void* d_out, int out_size, void* d_ws, size_t ws_size,
                              hipStream_t stream) {
    const float* x   = (const float*)d_in[0];
    const int*   ind = (const int*)d_in[1];
    const float* Wq  = (const float*)d_in[2];
    const float* Wk  = (const float*)d_in[3];
    const float* Wv  = (const float*)d_in[4];
    const float* Wo  = (const float*)d_in[5];
    const float* bq  = (const float*)d_in[6];
    const float* bk  = (const float*)d_in[7];
    const float* bv  = (const float*)d_in[8];
    const float* bo  = (const float*)d_in[9];
    const float* g1  = (const float*)d_in[10];
    const float* be1 = (const float*)d_in[11];
    const float* W1  = (const float*)d_in[12];
    const float* b1  = (const float*)d_in[13];
    const float* W2  = (const float*)d_in[14];
    const float* b2  = (const float*)d_in[15];
    const float* g2  = (const float*)d_in[16];
    const float* be2 = (const float*)d_in[17];
    float* out = (float*)d_out;
    (void)in_sizes; (void)n_in; (void)out_size;

    char* ws = (char*)d_ws;
    const size_t phb  = (size_t)NR * 256 * sizeof(u16);   // per-head tensor bytes
    const size_t accb = (size_t)NR * DD * sizeof(float);

    // Choose the largest head-group G whose footprint fits ws_size.
    int G = 8;
    while (G > 1 && (512 + 3 * (size_t)G * phb + accb) > ws_size) G >>= 1;
    int QS = 512 / (BB * G); if (QS < 1) QS = 1;          // q-chunk split for occupancy

    int* starts = (int*)ws;
    u16* q = (u16*)(ws + 512);
    u16* k = q + (size_t)G * NR * 256;
    u16* v = k + (size_t)G * NR * 256;
    float* acc = (float*)(ws + 512 + 3 * (size_t)G * phb);
    u16* o = q;                 // alias: safe (see k_attn comment)
    float* hbuf = (float*)q;    // alias: LN1 runs after last proj pass
    float* rowout = acc;        // alias: FFN runs after LN1, acc dead

    hipLaunchKernelGGL(k_starts,   dim3(1),  dim3(128), 0, stream, ind, starts);
    hipLaunchKernelGGL(k_init_acc, dim3(NR), dim3(256), 0, stream, x, bo, acc);
    for (int h0 = 0; h0 < HH; h0 += G) {
        hipLaunchKernelGGL(k_qkv,  dim3(NR / 64, G * 4, 3), dim3(256), 0, stream,
                           x, Wq, Wk, Wv, bq, bk, bv, q, k, v, G, h0);
        hipLaunchKernelGGL(k_attn, dim3(BB * G, QS),        dim3(256), 0, stream,
                           q, k, v, o, starts, G, QS);
        hipLaunchKernelGGL(k_proj, dim3(NR / 16),           dim3(256), 0, stream,
                           o, Wo, acc, G, h0);
    }
    hipLaunchKernelGGL(k_ln1,  dim3(NR / 4),  dim3(256), 0, stream, acc, g1, be1, hbuf);
    hipLaunchKernelGGL(k_ffn,  dim3(NR / 16), dim3(256), 0, stream,
                       hbuf, W1, b1, W2, b2, g2, be2, rowout);
    hipLaunchKernelGGL(k_pool, dim3(BB),      dim3(256), 0, stream, rowout, starts, out);
}

// Round 3
// 7071.840 us; speedup vs baseline: 1.3150x; 1.3150x over previous
//
#include <hip/hip_runtime.h>
#include <cstdint>
#include <cstddef>

#define NTOT 25600
#define BB 64
#define MAXN 512
#define DD 256
#define HH 8
#define FF 1024
#define HK 2048
#define NR (NTOT + BB)   // real rows + 1 pad-representative per batch
#define MT ((NR + 127) / 128)   // 201 M-tiles
#define EPS 1e-3f

typedef unsigned short u16;
typedef unsigned int   u32;
typedef __attribute__((ext_vector_type(8))) short s8v;   // 8 bf16 (4 VGPRs)
typedef __attribute__((ext_vector_type(4))) float f4v;   // MFMA accumulator

__device__ __forceinline__ float bf2f(u16 u) { return __uint_as_float(((u32)u) << 16); }
__device__ __forceinline__ u16 f2bf(float f) {
    u32 x = __float_as_uint(f);
    return (u16)((x + 0x7fffu + ((x >> 16) & 1u)) >> 16);  // RNE; inputs finite
}

// ---------------- K1: segment starts via binary search (indicator sorted) ----
__global__ void k_starts(const int* __restrict__ ind, int* __restrict__ starts) {
    int b = threadIdx.x;
    if (b > BB) return;
    int lo = 0, hi = NTOT;
    while (lo < hi) { int mid = (lo + hi) >> 1; if (ind[mid] < b) lo = mid + 1; else hi = mid; }
    starts[b] = lo;   // starts[64] == NTOT
}

// ---------------- K2: cast x -> bf16 (pad-rep rows = 0) ----------------------
__global__ __launch_bounds__(256) void k_cast_x(
    const float* __restrict__ x, u16* __restrict__ x16) {
    int row = blockIdx.x, t = threadIdx.x;
    float v = (row < NTOT) ? x[(size_t)row * DD + t] : 0.f;
    x16[(size_t)row * DD + t] = f2bf(v);
}

// ---------------- K3: transpose+cast weight W[Kd][Nd] -> WT[Nd][Kd] bf16 -----
__global__ __launch_bounds__(256) void k_transp(
    const float* __restrict__ W, u16* __restrict__ WT, int lgK, int Nd) {
    int id = blockIdx.x * 256 + threadIdx.x;
    int k = id & ((1 << lgK) - 1);
    int n = id >> lgK;
    WT[((size_t)n << lgK) | k] = f2bf(W[(size_t)k * Nd + n]);
}

// ---------------- K4: acc = x + bo (pad-rep rows: bo only) -------------------
__global__ __launch_bounds__(256) void k_init_acc(
    const float* __restrict__ x, const float* __restrict__ bo, float* __restrict__ acc) {
    int row = blockIdx.x, t = threadIdx.x;
    float v = bo[t];
    if (row < NTOT) v += x[(size_t)row * DD + t];
    acc[(size_t)row * DD + t] = v;
}

// ---------------- MFMA GEMM core: C[128x128] = A[128xkw] * BT[128 rows][kw] --
// A row-major [M][lda] bf16; BT row-major [N][ldb] bf16 (row n = output col n),
// k window [kbeg, kbeg+kw). acc layout: col = lane&15, row = (lane>>4)*4+reg.
__device__ __forceinline__ void gemm_core(
    const u16* __restrict__ A, int lda,
    const u16* __restrict__ BT, int ldb, int kbeg, int kw,
    int M, int m0, int n0, f4v acc[4][4])
{
    __shared__ u16 As[128 * 64];
    __shared__ u16 Bs[128 * 64];
    int t = threadIdx.x;
    int l = t & 63, w = t >> 6;
    int wm = (w >> 1) * 64, wn = (w & 1) * 64;
    const f4v z4 = {0.f, 0.f, 0.f, 0.f};
#pragma unroll
    for (int i = 0; i < 4; ++i)
#pragma unroll
        for (int j = 0; j < 4; ++j) acc[i][j] = z4;

    for (int k0 = 0; k0 < kw; k0 += 64) {
#pragma unroll
        for (int it = 0; it < 4; ++it) {   // stage A and B tiles (reg-staged)
            int chunk = it * 256 + t;
            int r = chunk >> 3, c8 = (chunk & 7) * 8;
            int ga = m0 + r; ga = (ga < M) ? ga : (M - 1);   // clamp: no OOB fault
            s8v va = *reinterpret_cast<const s8v*>(&A[(size_t)ga * lda + k0 + c8]);
            *reinterpret_cast<s8v*>(&As[r * 64 + c8]) = va;
            s8v vb = *reinterpret_cast<const s8v*>(&BT[(size_t)(n0 + r) * ldb + kbeg + k0 + c8]);
            *reinterpret_cast<s8v*>(&Bs[r * 64 + c8]) = vb;
        }
        __syncthreads();
#pragma unroll
        for (int ks = 0; ks < 64; ks += 32) {
            s8v af[4], bf[4];
#pragma unroll
            for (int mt = 0; mt < 4; ++mt)
                af[mt] = *reinterpret_cast<const s8v*>(&As[(wm + mt * 16 + (l & 15)) * 64 + ks + (l >> 4) * 8]);
#pragma unroll
            for (int nt = 0; nt < 4; ++nt)
                bf[nt] = *reinterpret_cast<const s8v*>(&Bs[(wn + nt * 16 + (l & 15)) * 64 + ks + (l >> 4) * 8]);
#pragma unroll
            for (int mt = 0; mt < 4; ++mt)
#pragma unroll
                for (int nt = 0; nt < 4; ++nt)
                    acc[mt][nt] = __builtin_amdgcn_mfma_f32_16x16x32_bf16(af[mt], bf[nt], acc[mt][nt], 0, 0, 0);
        }
        __syncthreads();
    }
}

// ---------------- K5: QKV projection (MFMA), head group [h0, h0+G) ----------
__global__ __launch_bounds__(256) void k_qkv_mfma(
    const u16* __restrict__ x16,
    const u16* __restrict__ WqT, const u16* __restrict__ WkT, const u16* __restrict__ WvT,
    const float* __restrict__ bq, const float* __restrict__ bk, const float* __restrict__ bv,
    u16* __restrict__ q, u16* __restrict__ k, u16* __restrict__ v, int G, int h0)
{
    int z = blockIdx.z;
    const u16* BT     = (z == 0) ? WqT : ((z == 1) ? WkT : WvT);
    const float* bias = (z == 0) ? bq  : ((z == 1) ? bk  : bv);
    u16* out          = (z == 0) ? q   : ((z == 1) ? k   : v);
    int S = G << 8;
    int m0 = blockIdx.x * 128, n0 = blockIdx.y * 128;
    f4v acc[4][4];
    gemm_core(x16, DD, BT + (size_t)(h0 << 8) * DD, DD, 0, DD, NR, m0, n0, acc);
    bias += (h0 << 8);
    int l = threadIdx.x & 63, w = threadIdx.x >> 6;
    int wm = (w >> 1) * 64, wn = (w & 1) * 64;
#pragma unroll
    for (int mt = 0; mt < 4; ++mt)
#pragma unroll
        for (int reg = 0; reg < 4; ++reg) {
            int row = m0 + wm + mt * 16 + (l >> 4) * 4 + reg;
            if (row >= NR) continue;
#pragma unroll
            for (int nt = 0; nt < 4; ++nt) {
                int col = n0 + wn + nt * 16 + (l & 15);
                out[(size_t)row * S + col] = f2bf(acc[mt][nt][reg] + bias[col]);
            }
        }
}

// ---------------- K6: attention per (b, h in group) — unchanged (round 2) ---
__global__ __launch_bounds__(256) void k_attn(
    const u16* __restrict__ q, const u16* __restrict__ kb, const u16* __restrict__ vb,
    u16* __restrict__ o, const int* __restrict__ starts, int G, int QS)
{
    int b = blockIdx.x / G;
    int h = blockIdx.x % G;
    int S = G << 8;
    int t = threadIdx.x;
    int lane = t & 63, wid = t >> 6;
    int start = starts[b];
    int N = starts[b + 1] - start;
    if (N > MAXN) N = MAXN;
    int R = N + 1;
    __shared__ __align__(16) float q_lds[8][261];
    __shared__ __align__(16) float k_lds[32][261];
    __shared__ float p[8][512];
    __shared__ float red4[4];
    __shared__ float ssum[8];
    size_t hoff = (size_t)h << 8;

    if (N == 0) {
        if (blockIdx.y == 0) {
            int g = NTOT + b;
            o[(size_t)g * S + hoff + t] = vb[(size_t)g * S + hoff + t];
        }
        return;
    }

    int nqb = (R + 7) >> 3;
    for (int qb = blockIdx.y; qb < nqb; qb += QS) {
        {
            int qr = t >> 5, f0 = (t & 31) * 8;
            int qi = qb * 8 + qr;
            float vals[8];
            if (qi < R) {
                int g = (qi < N) ? (start + qi) : (NTOT + b);
                uint4 raw = *reinterpret_cast<const uint4*>(&q[(size_t)g * S + hoff + f0]);
                u32 wrd[4] = {raw.x, raw.y, raw.z, raw.w};
#pragma unroll
                for (int e = 0; e < 4; ++e) {
                    vals[2 * e]     = bf2f((u16)(wrd[e] & 0xffffu));
                    vals[2 * e + 1] = bf2f((u16)(wrd[e] >> 16));
                }
            } else {
#pragma unroll
                for (int e = 0; e < 8; ++e) vals[e] = 0.f;
            }
#pragma unroll
            for (int e = 0; e < 8; ++e) q_lds[qr][f0 + e] = vals[e];
        }
        __syncthreads();

        int nkt = (N + 31) >> 5;
        for (int kt = 0; kt < nkt; ++kt) {
            {
                int kr = t >> 3, f0 = (t & 7) * 32;
                int ml = kt * 32 + kr;
                if (ml < N) {
                    int g = start + ml;
#pragma unroll
                    for (int it = 0; it < 4; ++it) {
                        int f = f0 + it * 8;
                        uint4 raw = *reinterpret_cast<const uint4*>(&kb[(size_t)g * S + hoff + f]);
                        u32 wrd[4] = {raw.x, raw.y, raw.z, raw.w};
#pragma unroll
                        for (int e = 0; e < 4; ++e) {
                            k_lds[kr][f + 2 * e]     = bf2f((u16)(wrd[e] & 0xffffu));
                            k_lds[kr][f + 2 * e + 1] = bf2f((u16)(wrd[e] >> 16));
                        }
                    }
                }
            }
            __syncthreads();
            {
                int qr = t >> 5, kk = t & 31;
                int m = kt * 32 + kk;
                if (m < N) {
                    float acc = 0.f;
#pragma unroll 8
                    for (int j = 0; j < 256; ++j) acc += q_lds[qr][j] * k_lds[kk][j];
                    p[qr][m] = acc * 0.0625f;
                }
            }
            __syncthreads();
        }

        for (int qr = 0; qr < 8; ++qr) {
            int qi = qb * 8 + qr;
            bool valid = (qi < R);
            float lm = -1e30f;
            if (valid) for (int m = t; m < N; m += 256) lm = fmaxf(lm, p[qr][m]);
#pragma unroll
            for (int off = 32; off > 0; off >>= 1) lm = fmaxf(lm, __shfl_xor(lm, off, 64));
            if (lane == 0) red4[wid] = lm;
            __syncthreads();
            float mx = fmaxf(fmaxf(red4[0], red4[1]), fmaxf(red4[2], red4[3]));
            __syncthreads();
            float ls = 0.f;
            if (valid) for (int m = t; m < N; m += 256) {
                float e = __expf(p[qr][m] - mx);
                p[qr][m] = e;
                ls += e;
            }
#pragma unroll
            for (int off = 32; off > 0; off >>= 1) ls += __shfl_xor(ls, off, 64);
            if (lane == 0) red4[wid] = ls;
            __syncthreads();
            if (t == 0) ssum[qr] = red4[0] + red4[1] + red4[2] + red4[3];
            __syncthreads();
        }

        {
            float acc8[8];
#pragma unroll
            for (int i = 0; i < 8; ++i) acc8[i] = 0.f;
            for (int m = 0; m < N; ++m) {
                float vv = bf2f(vb[(size_t)(start + m) * S + hoff + t]);
#pragma unroll
                for (int qr = 0; qr < 8; ++qr) acc8[qr] += p[qr][m] * vv;
            }
#pragma unroll
            for (int qr = 0; qr < 8; ++qr) {
                int qi = qb * 8 + qr;
                if (qi < R) {
                    int g = (qi < N) ? (start + qi) : (NTOT + b);
                    o[(size_t)g * S + hoff + t] = f2bf(acc8[qr] / ssum[qr]);
                }
            }
        }
        __syncthreads();
    }
}

// ---------------- K7: acc += o @ Wo (MFMA, K-slice = this head group) --------
__global__ __launch_bounds__(256) void k_proj_mfma(
    const u16* __restrict__ o, const u16* __restrict__ WoT,
    float* __restrict__ acc, int G, int h0)
{
    int S = G << 8;
    int m0 = blockIdx.x * 128, n0 = blockIdx.y * 128;
    f4v av[4][4];
    gemm_core(o, S, WoT, HK, h0 << 8, S, NR, m0, n0, av);
    int l = threadIdx.x & 63, w = threadIdx.x >> 6;
    int wm = (w >> 1) * 64, wn = (w & 1) * 64;
#pragma unroll
    for (int mt = 0; mt < 4; ++mt)
#pragma unroll
        for (int reg = 0; reg < 4; ++reg) {
            int row = m0 + wm + mt * 16 + (l >> 4) * 4 + reg;
            if (row >= NR) continue;
#pragma unroll
            for (int nt = 0; nt < 4; ++nt) {
                int col = n0 + wn + nt * 16 + (l & 15);
                acc[(size_t)row * DD + col] += av[mt][nt][reg];   // one owner/elem
            }
        }
}

// ---------------- K8: LayerNorm (optionally also emit bf16 copy) -------------
__global__ __launch_bounds__(256) void k_ln(
    const float* __restrict__ in, const float* __restrict__ g, const float* __restrict__ be,
    float* __restrict__ outf, u16* __restrict__ out16)
{
    int w = threadIdx.x >> 6, lane = threadIdx.x & 63;
    int row = blockIdx.x * 4 + w;
    const float* a = &in[(size_t)row * DD];
    float v0 = a[lane], v1 = a[lane + 64], v2 = a[lane + 128], v3 = a[lane + 192];
    float s  = v0 + v1 + v2 + v3;
    float ss = v0 * v0 + v1 * v1 + v2 * v2 + v3 * v3;
#pragma unroll
    for (int off = 32; off > 0; off >>= 1) { s += __shfl_xor(s, off, 64); ss += __shfl_xor(ss, off, 64); }
    float mean = s * (1.f / 256.f);
    float var  = ss * (1.f / 256.f) - mean * mean;
    float rstd = rsqrtf(var + EPS);
    float r0 = (v0 - mean) * rstd * g[lane]       + be[lane];
    float r1 = (v1 - mean) * rstd * g[lane + 64]  + be[lane + 64];
    float r2 = (v2 - mean) * rstd * g[lane + 128] + be[lane + 128];
    float r3 = (v3 - mean) * rstd * g[lane + 192] + be[lane + 192];
    float* of = &outf[(size_t)row * DD];
    of[lane] = r0; of[lane + 64] = r1; of[lane + 128] = r2; of[lane + 192] = r3;
    if (out16) {
        u16* o6 = &out16[(size_t)row * DD];
        o6[lane] = f2bf(r0); o6[lane + 64] = f2bf(r1);
        o6[lane + 128] = f2bf(r2); o6[lane + 192] = f2bf(r3);
    }
}

// ---------------- K9: FFN1 (MFMA): ff16 = relu(h16 @ W1 + b1) ----------------
__global__ __launch_bounds__(256) void k_ffn1_mfma(
    const u16* __restrict__ h16, const u16* __restrict__ W1T, const float* __restrict__ b1,
    u16* __restrict__ ff16)
{
    int m0 = blockIdx.x * 128, n0 = blockIdx.y * 128;
    f4v acc[4][4];
    gemm_core(h16, DD, W1T, DD, 0, DD, NR, m0, n0, acc);
    int l = threadIdx.x & 63, w = threadIdx.x >> 6;
    int wm = (w >> 1) * 64, wn = (w & 1) * 64;
#pragma unroll
    for (int mt = 0; mt < 4; ++mt)
#pragma unroll
        for (int reg = 0; reg < 4; ++reg) {
            int row = m0 + wm + mt * 16 + (l >> 4) * 4 + reg;
            if (row >= NR) continue;
#pragma unroll
            for (int nt = 0; nt < 4; ++nt) {
                int col = n0 + wn + nt * 16 + (l & 15);
                ff16[(size_t)row * FF + col] = f2bf(fmaxf(acc[mt][nt][reg] + b1[col], 0.f));
            }
        }
}

// ---------------- K10: FFN2 (MFMA): ff2 = ff16 @ W2 + b2 + h (residual) ------
__global__ __launch_bounds__(256) void k_ffn2_mfma(
    const u16* __restrict__ ff16, const u16* __restrict__ W2T, const float* __restrict__ b2,
    const float* __restrict__ hbuf, float* __restrict__ outf)
{
    int m0 = blockIdx.x * 128, n0 = blockIdx.y * 128;
    f4v acc[4][4];
    gemm_core(ff16, FF, W2T, FF, 0, FF, NR, m0, n0, acc);
    int l = threadIdx.x & 63, w = threadIdx.x >> 6;
    int wm = (w >> 1) * 64, wn = (w & 1) * 64;
#pragma unroll
    for (int mt = 0; mt < 4; ++mt)
#pragma unroll
        for (int reg = 0; reg < 4; ++reg) {
            int row = m0 + wm + mt * 16 + (l >> 4) * 4 + reg;
            if (row >= NR) continue;
#pragma unroll
            for (int nt = 0; nt < 4; ++nt) {
                int col = n0 + wn + nt * 16 + (l & 15);
                outf[(size_t)row * DD + col] = acc[mt][nt][reg] + b2[col] + hbuf[(size_t)row * DD + col];
            }
        }
}

// ---------------- K11: pooled readout ---------------------------------------
__global__ void k_pool(const float* __restrict__ rowout, const int* __restrict__ starts,
                       float* __restrict__ out)
{
    int b = blockIdx.x; int d = threadIdx.x;
    int start = starts[b];
    int N = starts[b + 1] - start;
    if (N > MAXN) N = MAXN;
    float s = 0.f;
    for (int n = 0; n < N; ++n) s += rowout[(size_t)(start + n) * DD + d];
    s += (float)(MAXN - N) * rowout[(size_t)(NTOT + b) * DD + d];
    out[(size_t)b * DD + d] = s * (1.f / 512.f);
}

extern "C" void kernel_launch(void* const* d_in, const int* in_sizes, int n_in,
                              void* d_out, int out_size, void* d_ws, size_t ws_size,
                              hipStream_t stream) {
    const float* x   = (const float*)d_in[0];
    const int*   ind = (const int*)d_in[1];
    const float* Wq  = (const float*)d_in[2];
    const float* Wk  = (const float*)d_in[3];
    const float* Wv  = (const float*)d_in[4];
    const float* Wo  = (const float*)d_in[5];
    const float* bq  = (const float*)d_in[6];
    const float* bk  = (const float*)d_in[7];
    const float* bv  = (const float*)d_in[8];
    const float* bo  = (const float*)d_in[9];
    const float* g1  = (const float*)d_in[10];
    const float* be1 = (const float*)d_in[11];
    const float* W1  = (const float*)d_in[12];
    const float* b1  = (const float*)d_in[13];
    const float* W2  = (const float*)d_in[14];
    const float* b2  = (const float*)d_in[15];
    const float* g2  = (const float*)d_in[16];
    const float* be2 = (const float*)d_in[17];
    float* out = (float*)d_out;
    (void)in_sizes; (void)n_in; (void)out_size;

    char* ws = (char*)d_ws;
    const size_t rb2 = (size_t)NR * DD * sizeof(u16);    // 13.1 MB
    const size_t rb4 = (size_t)NR * DD * sizeof(float);  // 26.3 MB
    const size_t ffb = (size_t)NR * FF * sizeof(u16);    // 52.5 MB
    const size_t wq_b = (size_t)HK * DD * sizeof(u16);   // 1 MB each qkv/Wo
    const size_t w1_b = (size_t)FF * DD * sizeof(u16);   // 0.5 MB each W1/W2
    const size_t fixed = 512 + 2 * rb4 + 2 * rb2 + ffb + 4 * wq_b + 2 * w1_b;

    int G = 8;   // largest head-group whose footprint fits
    while (G > 1 && fixed + 3 * (size_t)G * rb2 > ws_size) G >>= 1;
    int QS = 512 / (BB * G); if (QS < 1) QS = 1;

    size_t off = 0;
    int* starts = (int*)ws;              off += 512;
    u16* q   = (u16*)(ws + off);         off += (size_t)G * rb2;
    u16* k   = (u16*)(ws + off);         off += (size_t)G * rb2;
    u16* v   = (u16*)(ws + off);         off += (size_t)G * rb2;
    float* acc  = (float*)(ws + off);    off += rb4;
    float* hbuf = (float*)(ws + off);    off += rb4;
    u16* x16 = (u16*)(ws + off);         off += rb2;
    u16* h16 = (u16*)(ws + off);         off += rb2;
    u16* ff16 = (u16*)(ws + off);        off += ffb;
    u16* WqT = (u16*)(ws + off);         off += wq_b;
    u16* WkT = (u16*)(ws + off);         off += wq_b;
    u16* WvT = (u16*)(ws + off);         off += wq_b;
    u16* WoT = (u16*)(ws + off);         off += wq_b;
    u16* W1T = (u16*)(ws + off);         off += w1_b;
    u16* W2T = (u16*)(ws + off);         off += w1_b;
    u16* o = q;   // alias: safe (attn stages q rows to LDS before writing o)

    hipLaunchKernelGGL(k_starts,   dim3(1),    dim3(128), 0, stream, ind, starts);
    hipLaunchKernelGGL(k_cast_x,   dim3(NR),   dim3(256), 0, stream, x, x16);
    hipLaunchKernelGGL(k_transp,   dim3(2048), dim3(256), 0, stream, Wq, WqT, 8, HK);
    hipLaunchKernelGGL(k_transp,   dim3(2048), dim3(256), 0, stream, Wk, WkT, 8, HK);
    hipLaunchKernelGGL(k_transp,   dim3(2048), dim3(256), 0, stream, Wv, WvT, 8, HK);
    hipLaunchKernelGGL(k_transp,   dim3(2048), dim3(256), 0, stream, Wo, WoT, 11, DD);
    hipLaunchKernelGGL(k_transp,   dim3(1024), dim3(256), 0, stream, W1, W1T, 8, FF);
    hipLaunchKernelGGL(k_transp,   dim3(1024), dim3(256), 0, stream, W2, W2T, 10, DD);
    hipLaunchKernelGGL(k_init_acc, dim3(NR),   dim3(256), 0, stream, x, bo, acc);
    for (int h0 = 0; h0 < HH; h0 += G) {
        hipLaunchKernelGGL(k_qkv_mfma,  dim3(MT, 2 * G, 3), dim3(256), 0, stream,
                           x16, WqT, WkT, WvT, bq, bk, bv, q, k, v, G, h0);
        hipLaunchKernelGGL(k_attn,      dim3(BB * G, QS),   dim3(256), 0, stream,
                           q, k, v, o, starts, G, QS);
        hipLaunchKernelGGL(k_proj_mfma, dim3(MT, 2),        dim3(256), 0, stream,
                           o, WoT, acc, G, h0);
    }
    hipLaunchKernelGGL(k_ln,        dim3(NR / 4), dim3(256), 0, stream, acc, g1, be1, hbuf, h16);
    hipLaunchKernelGGL(k_ffn1_mfma, dim3(MT, 8),  dim3(256), 0, stream, h16, W1T, b1, ff16);
    hipLaunchKernelGGL(k_ffn2_mfma, dim3(MT, 2),  dim3(256), 0, stream, ff16, W2T, b2, hbuf, acc);
    hipLaunchKernelGGL(k_ln,        dim3(NR / 4), dim3(256), 0, stream, acc, g2, be2, acc, (u16*)nullptr);
    hipLaunchKernelGGL(k_pool,      dim3(BB),     dim3(256), 0, stream, acc, starts, out);
}

// Round 4
// 1010.955 us; speedup vs baseline: 9.1988x; 6.9952x over previous
//
#include <hip/hip_runtime.h>
#include <cstdint>
#include <cstddef>

#define NTOT 25600
#define BB 64
#define MAXN 512
#define DD 256
#define HH 8
#define FF 1024
#define HK 2048
#define NR (NTOT + BB)          // real rows + 1 pad-representative per batch
#define NK (BB * MAXN)          // 32768: vt column space (per-batch 512-aligned)
#define MT ((NR + 127) / 128)   // 201 M-tiles
#define QT 9                    // ceil((MAXN+1)/64) q-tiles
#define EPS 1e-3f

typedef unsigned short u16;
typedef unsigned int   u32;
typedef __attribute__((ext_vector_type(8))) short s8v;   // 8 bf16 (4 VGPRs)
typedef __attribute__((ext_vector_type(4))) float f4v;   // MFMA accumulator

__device__ __forceinline__ float bf2f(u16 u) { return __uint_as_float(((u32)u) << 16); }
__device__ __forceinline__ u16 f2bf(float f) {
    u32 x = __float_as_uint(f);
    return (u16)((x + 0x7fffu + ((x >> 16) & 1u)) >> 16);  // RNE; inputs finite
}

// ---------------- K1: segment starts via binary search (indicator sorted) ----
__global__ void k_starts(const int* __restrict__ ind, int* __restrict__ starts) {
    int b = threadIdx.x;
    if (b > BB) return;
    int lo = 0, hi = NTOT;
    while (lo < hi) { int mid = (lo + hi) >> 1; if (ind[mid] < b) lo = mid + 1; else hi = mid; }
    starts[b] = lo;   // starts[64] == NTOT
}

// ---------------- K1b: row -> b*512 + local_pos map (-1 if beyond 512) -------
__global__ __launch_bounds__(256) void k_rowmap(const int* __restrict__ starts,
                                                int* __restrict__ rmap) {
    int row = blockIdx.x * 256 + threadIdx.x;
    if (row >= NTOT) return;
    int lo = 0, hi = BB - 1;
    while (lo < hi) { int mid = (lo + hi + 1) >> 1; if (starts[mid] <= row) lo = mid; else hi = mid - 1; }
    int m = row - starts[lo];
    rmap[row] = (m < MAXN) ? ((lo << 9) + m) : -1;
}

// ---------------- K2: cast x -> bf16 (pad-rep rows = 0) ----------------------
__global__ __launch_bounds__(256) void k_cast_x(
    const float* __restrict__ x, u16* __restrict__ x16) {
    int row = blockIdx.x, t = threadIdx.x;
    float v = (row < NTOT) ? x[(size_t)row * DD + t] : 0.f;
    x16[(size_t)row * DD + t] = f2bf(v);
}

// ---------------- K3: transpose+cast weight W[Kd][Nd] -> WT[Nd][Kd] bf16 -----
__global__ __launch_bounds__(256) void k_transp(
    const float* __restrict__ W, u16* __restrict__ WT, int lgK, int Nd) {
    int id = blockIdx.x * 256 + threadIdx.x;
    int k = id & ((1 << lgK) - 1);
    int n = id >> lgK;
    WT[((size_t)n << lgK) | k] = f2bf(W[(size_t)k * Nd + n]);
}

// ---------------- K4: acc = x + bo (pad-rep rows: bo only) -------------------
__global__ __launch_bounds__(256) void k_init_acc(
    const float* __restrict__ x, const float* __restrict__ bo, float* __restrict__ acc) {
    int row = blockIdx.x, t = threadIdx.x;
    float v = bo[t];
    if (row < NTOT) v += x[(size_t)row * DD + t];
    acc[(size_t)row * DD + t] = v;
}

// ---------------- MFMA GEMM core (verified R3): C[128x128]=A[128xkw]*BT^T ----
__device__ __forceinline__ void gemm_core(
    const u16* __restrict__ A, int lda,
    const u16* __restrict__ BT, int ldb, int kbeg, int kw,
    int M, int m0, int n0, f4v acc[4][4])
{
    __shared__ u16 As[128 * 64];
    __shared__ u16 Bs[128 * 64];
    int t = threadIdx.x;
    int l = t & 63, w = t >> 6;
    int wm = (w >> 1) * 64, wn = (w & 1) * 64;
    const f4v z4 = {0.f, 0.f, 0.f, 0.f};
#pragma unroll
    for (int i = 0; i < 4; ++i)
#pragma unroll
        for (int j = 0; j < 4; ++j) acc[i][j] = z4;

    for (int k0 = 0; k0 < kw; k0 += 64) {
#pragma unroll
        for (int it = 0; it < 4; ++it) {
            int chunk = it * 256 + t;
            int r = chunk >> 3, c8 = (chunk & 7) * 8;
            int ga = m0 + r; ga = (ga < M) ? ga : (M - 1);
            s8v va = *reinterpret_cast<const s8v*>(&A[(size_t)ga * lda + k0 + c8]);
            *reinterpret_cast<s8v*>(&As[r * 64 + c8]) = va;
            s8v vb = *reinterpret_cast<const s8v*>(&BT[(size_t)(n0 + r) * ldb + kbeg + k0 + c8]);
            *reinterpret_cast<s8v*>(&Bs[r * 64 + c8]) = vb;
        }
        __syncthreads();
#pragma unroll
        for (int ks = 0; ks < 64; ks += 32) {
            s8v af[4], bf[4];
#pragma unroll
            for (int mt = 0; mt < 4; ++mt)
                af[mt] = *reinterpret_cast<const s8v*>(&As[(wm + mt * 16 + (l & 15)) * 64 + ks + (l >> 4) * 8]);
#pragma unroll
            for (int nt = 0; nt < 4; ++nt)
                bf[nt] = *reinterpret_cast<const s8v*>(&Bs[(wn + nt * 16 + (l & 15)) * 64 + ks + (l >> 4) * 8]);
#pragma unroll
            for (int mt = 0; mt < 4; ++mt)
#pragma unroll
                for (int nt = 0; nt < 4; ++nt)
                    acc[mt][nt] = __builtin_amdgcn_mfma_f32_16x16x32_bf16(af[mt], bf[nt], acc[mt][nt], 0, 0, 0);
        }
        __syncthreads();
    }
}

// ---------------- K5: QKV projection (MFMA). z==2 writes V pre-transposed ----
__global__ __launch_bounds__(256) void k_qkv_mfma(
    const u16* __restrict__ x16,
    const u16* __restrict__ WqT, const u16* __restrict__ WkT, const u16* __restrict__ WvT,
    const float* __restrict__ bq, const float* __restrict__ bk, const float* __restrict__ bv,
    u16* __restrict__ q, u16* __restrict__ k, u16* __restrict__ vt,
    const int* __restrict__ rmap, int G, int h0)
{
    int z = blockIdx.z;
    const u16* BT     = (z == 0) ? WqT : ((z == 1) ? WkT : WvT);
    const float* bias = (z == 0) ? bq  : ((z == 1) ? bk  : bv);
    int S = G << 8;
    int m0 = blockIdx.x * 128, n0 = blockIdx.y * 128;
    f4v acc[4][4];
    gemm_core(x16, DD, BT + (size_t)(h0 << 8) * DD, DD, 0, DD, NR, m0, n0, acc);
    bias += (h0 << 8);
    int l = threadIdx.x & 63, w = threadIdx.x >> 6;
    int wm = (w >> 1) * 64, wn = (w & 1) * 64;
    if (z < 2) {
        u16* out = (z == 0) ? q : k;
#pragma unroll
        for (int mt = 0; mt < 4; ++mt)
#pragma unroll
            for (int reg = 0; reg < 4; ++reg) {
                int row = m0 + wm + mt * 16 + (l >> 4) * 4 + reg;
                if (row >= NR) continue;
#pragma unroll
                for (int nt = 0; nt < 4; ++nt) {
                    int col = n0 + wn + nt * 16 + (l & 15);
                    out[(size_t)row * S + col] = f2bf(acc[mt][nt][reg] + bias[col]);
                }
            }
    } else {   // V transposed: vt[col][b*512 + m]
#pragma unroll
        for (int mt = 0; mt < 4; ++mt)
#pragma unroll
            for (int reg = 0; reg < 4; ++reg) {
                int row = m0 + wm + mt * 16 + (l >> 4) * 4 + reg;
                if (row >= NTOT) continue;
                int rm_ = rmap[row];
                if (rm_ < 0) continue;
#pragma unroll
                for (int nt = 0; nt < 4; ++nt) {
                    int col = n0 + wn + nt * 16 + (l & 15);
                    vt[(size_t)col * NK + rm_] = f2bf(acc[mt][nt][reg] + bias[col]);
                }
            }
    }
}

// ---------------- K6: MFMA flash attention per (b, h, q-tile of 64 rows) -----
// Q in regs; K staged in LDS [32][264]; V^T staged in LDS [256][40] (global vt
// is pre-transposed so staging is a linear copy); P bounced via wave-private
// LDS tile (C-layout -> A-layout). Online softmax in registers, exact
// defer-rescale (skip when tile max doesn't grow). o aliases q: each wg reads
// only its own q rows (into regs, before any o write) -> safe.
__global__ __launch_bounds__(256) void k_attn_mfma(
    const u16* __restrict__ q, const u16* __restrict__ kb, const u16* __restrict__ vt,
    u16* __restrict__ o, const int* __restrict__ starts,
    const float* __restrict__ bv, int G, int h0)
{
    int b = blockIdx.x / G;
    int h = blockIdx.x % G;
    int S = G << 8;
    int t = threadIdx.x, l = t & 63, w = t >> 6;
    int lg = l >> 4, li = l & 15;
    int start = starts[b];
    int N = starts[b + 1] - start; if (N > MAXN) N = MAXN;
    int R = N + 1;
    int qt = blockIdx.y;
    if (qt * 64 >= R) return;
    size_t hoff = (size_t)h << 8;

    if (N == 0) {   // all rows pad: softmax uniform over identical rows -> o = v_pad = bv
        o[(size_t)(NTOT + b) * S + hoff + t] = f2bf(bv[((h0 + h) << 8) + t]);
        return;
    }

    __shared__ u16 k_lds[32 * 264];
    __shared__ u16 v_lds[256 * 40];
    __shared__ u16 p_lds[4][16 * 40];

    // Q fragments for this wave's 16 rows (row index within C = A row index)
    int qbase = qt * 64 + w * 16;
    int qiA = qbase + li; if (qiA > R - 1) qiA = R - 1;
    int growA = (qiA < N) ? (start + qiA) : (NTOT + b);
    const u16* qp = q + (size_t)growA * S + hoff;
    s8v qf[8];
#pragma unroll
    for (int ks = 0; ks < 8; ++ks)
        qf[ks] = *reinterpret_cast<const s8v*>(&qp[ks * 32 + lg * 8]);

    const f4v z4 = {0.f, 0.f, 0.f, 0.f};
    f4v O[16];
#pragma unroll
    for (int nt = 0; nt < 16; ++nt) O[nt] = z4;
    float m_run[4] = {-1e30f, -1e30f, -1e30f, -1e30f};
    float l_run[4] = {0.f, 0.f, 0.f, 0.f};

    const u16* vbh = vt + hoff * NK + (b << 9);

    int nkt = (N + 31) >> 5;
    for (int kt = 0; kt < nkt; ++kt) {
        __syncthreads();
        {   // stage K tile: 32 keys x 256 feats (coalesced global, linear LDS)
            int kr = t >> 3, f0 = (t & 7) * 32;
            int ml = kt * 32 + kr; if (ml >= N) ml = N - 1;   // clamped rows masked later
            const u16* kp = kb + (size_t)(start + ml) * S + hoff;
#pragma unroll
            for (int it = 0; it < 4; ++it)
                *reinterpret_cast<s8v*>(&k_lds[kr * 264 + f0 + it * 8]) =
                    *reinterpret_cast<const s8v*>(&kp[f0 + it * 8]);
        }
        {   // stage V^T tile: 256 feats x 32 keys (global already transposed)
            const u16* vp = vbh + (size_t)t * NK + kt * 32;
#pragma unroll
            for (int it = 0; it < 4; ++it)
                *reinterpret_cast<s8v*>(&v_lds[t * 40 + it * 8]) =
                    *reinterpret_cast<const s8v*>(&vp[it * 8]);
        }
        __syncthreads();

        // QK^T: C[q=row][key=col], two 16-key subtiles
        f4v s0 = z4, s1 = z4;
#pragma unroll
        for (int ks = 0; ks < 8; ++ks) {
            s8v kf0 = *reinterpret_cast<const s8v*>(&k_lds[li * 264 + ks * 32 + lg * 8]);
            s8v kf1 = *reinterpret_cast<const s8v*>(&k_lds[(16 + li) * 264 + ks * 32 + lg * 8]);
            s0 = __builtin_amdgcn_mfma_f32_16x16x32_bf16(qf[ks], kf0, s0, 0, 0, 0);
            s1 = __builtin_amdgcn_mfma_f32_16x16x32_bf16(qf[ks], kf1, s1, 0, 0, 0);
        }

        int key0 = kt * 32 + li, key1 = key0 + 16;
        float sm0[4], sm1[4], tm[4];
#pragma unroll
        for (int r = 0; r < 4; ++r) {
            sm0[r] = (key0 < N) ? s0[r] * 0.0625f : -1e30f;
            sm1[r] = (key1 < N) ? s1[r] * 0.0625f : -1e30f;
            float v2 = fmaxf(sm0[r], sm1[r]);
#pragma unroll
            for (int off = 8; off >= 1; off >>= 1) v2 = fmaxf(v2, __shfl_xor(v2, off, 64));
            tm[r] = v2;   // row max of this tile, replicated across 16-lane group
        }
        bool need = (tm[0] > m_run[0]) || (tm[1] > m_run[1]) ||
                    (tm[2] > m_run[2]) || (tm[3] > m_run[3]);
        if (__any(need)) {   // exact online-softmax rescale (THR=0)
#pragma unroll
            for (int r = 0; r < 4; ++r) {
                float mn = fmaxf(m_run[r], tm[r]);
                float sc = __expf(m_run[r] - mn);
                m_run[r] = mn; l_run[r] *= sc;
#pragma unroll
                for (int nt = 0; nt < 16; ++nt) O[nt][r] *= sc;
            }
        }
#pragma unroll
        for (int r = 0; r < 4; ++r) {
            u16 b0 = f2bf(__expf(sm0[r] - m_run[r]));
            u16 b1 = f2bf(__expf(sm1[r] - m_run[r]));
            p_lds[w][(lg * 4 + r) * 40 + li]      = b0;
            p_lds[w][(lg * 4 + r) * 40 + 16 + li] = b1;
            float sdum = bf2f(b0) + bf2f(b1);   // rounded p: num/denom consistency
#pragma unroll
            for (int off = 8; off >= 1; off >>= 1) sdum += __shfl_xor(sdum, off, 64);
            l_run[r] += sdum;
        }

        // PV: A = P (rows=q, k=keys), B = V^T rows (cols=feat, k=keys)
        s8v pa = *reinterpret_cast<const s8v*>(&p_lds[w][li * 40 + lg * 8]);
#pragma unroll
        for (int nt = 0; nt < 16; ++nt) {
            s8v vf = *reinterpret_cast<const s8v*>(&v_lds[(nt * 16 + li) * 40 + lg * 8]);
            O[nt] = __builtin_amdgcn_mfma_f32_16x16x32_bf16(pa, vf, O[nt], 0, 0, 0);
        }
    }

    // epilogue: normalize and store (C rows = (lg*4+reg), cols = nt*16+li)
#pragma unroll
    for (int r = 0; r < 4; ++r) {
        int qi = qbase + lg * 4 + r;
        if (qi >= R) continue;
        int grow = (qi < N) ? (start + qi) : (NTOT + b);
        float inv = 1.f / l_run[r];
        u16* op = o + (size_t)grow * S + hoff;
#pragma unroll
        for (int nt = 0; nt < 16; ++nt)
            op[nt * 16 + li] = f2bf(O[nt][r] * inv);
    }
}

// ---------------- K7: acc += o @ Wo (MFMA, K-slice = this head group) --------
__global__ __launch_bounds__(256) void k_proj_mfma(
    const u16* __restrict__ o, const u16* __restrict__ WoT,
    float* __restrict__ acc, int G, int h0)
{
    int S = G << 8;
    int m0 = blockIdx.x * 128, n0 = blockIdx.y * 128;
    f4v av[4][4];
    gemm_core(o, S, WoT, HK, h0 << 8, S, NR, m0, n0, av);
    int l = threadIdx.x & 63, w = threadIdx.x >> 6;
    int wm = (w >> 1) * 64, wn = (w & 1) * 64;
#pragma unroll
    for (int mt = 0; mt < 4; ++mt)
#pragma unroll
        for (int reg = 0; reg < 4; ++reg) {
            int row = m0 + wm + mt * 16 + (l >> 4) * 4 + reg;
            if (row >= NR) continue;
#pragma unroll
            for (int nt = 0; nt < 4; ++nt) {
                int col = n0 + wn + nt * 16 + (l & 15);
                acc[(size_t)row * DD + col] += av[mt][nt][reg];
            }
        }
}

// ---------------- K8: LayerNorm (optionally also emit bf16 copy) -------------
__global__ __launch_bounds__(256) void k_ln(
    const float* __restrict__ in, const float* __restrict__ g, const float* __restrict__ be,
    float* __restrict__ outf, u16* __restrict__ out16)
{
    int w = threadIdx.x >> 6, lane = threadIdx.x & 63;
    int row = blockIdx.x * 4 + w;
    const float* a = &in[(size_t)row * DD];
    float v0 = a[lane], v1 = a[lane + 64], v2 = a[lane + 128], v3 = a[lane + 192];
    float s  = v0 + v1 + v2 + v3;
    float ss = v0 * v0 + v1 * v1 + v2 * v2 + v3 * v3;
#pragma unroll
    for (int off = 32; off > 0; off >>= 1) { s += __shfl_xor(s, off, 64); ss += __shfl_xor(ss, off, 64); }
    float mean = s * (1.f / 256.f);
    float var  = ss * (1.f / 256.f) - mean * mean;
    float rstd = rsqrtf(var + EPS);
    float r0 = (v0 - mean) * rstd * g[lane]       + be[lane];
    float r1 = (v1 - mean) * rstd * g[lane + 64]  + be[lane + 64];
    float r2 = (v2 - mean) * rstd * g[lane + 128] + be[lane + 128];
    float r3 = (v3 - mean) * rstd * g[lane + 192] + be[lane + 192];
    float* of = &outf[(size_t)row * DD];
    of[lane] = r0; of[lane + 64] = r1; of[lane + 128] = r2; of[lane + 192] = r3;
    if (out16) {
        u16* o6 = &out16[(size_t)row * DD];
        o6[lane] = f2bf(r0); o6[lane + 64] = f2bf(r1);
        o6[lane + 128] = f2bf(r2); o6[lane + 192] = f2bf(r3);
    }
}

// ---------------- K9: FFN1 (MFMA): ff16 = relu(h16 @ W1 + b1) ----------------
__global__ __launch_bounds__(256) void k_ffn1_mfma(
    const u16* __restrict__ h16, const u16* __restrict__ W1T, const float* __restrict__ b1,
    u16* __restrict__ ff16)
{
    int m0 = blockIdx.x * 128, n0 = blockIdx.y * 128;
    f4v acc[4][4];
    gemm_core(h16, DD, W1T, DD, 0, DD, NR, m0, n0, acc);
    int l = threadIdx.x & 63, w = threadIdx.x >> 6;
    int wm = (w >> 1) * 64, wn = (w & 1) * 64;
#pragma unroll
    for (int mt = 0; mt < 4; ++mt)
#pragma unroll
        for (int reg = 0; reg < 4; ++reg) {
            int row = m0 + wm + mt * 16 + (l >> 4) * 4 + reg;
            if (row >= NR) continue;
#pragma unroll
            for (int nt = 0; nt < 4; ++nt) {
                int col = n0 + wn + nt * 16 + (l & 15);
                ff16[(size_t)row * FF + col] = f2bf(fmaxf(acc[mt][nt][reg] + b1[col], 0.f));
            }
        }
}

// ---------------- K10: FFN2 (MFMA): out = ff16 @ W2 + b2 + h (residual) ------
__global__ __launch_bounds__(256) void k_ffn2_mfma(
    const u16* __restrict__ ff16, const u16* __restrict__ W2T, const float* __restrict__ b2,
    const float* __restrict__ hbuf, float* __restrict__ outf)
{
    int m0 = blockIdx.x * 128, n0 = blockIdx.y * 128;
    f4v acc[4][4];
    gemm_core(ff16, FF, W2T, FF, 0, FF, NR, m0, n0, acc);
    int l = threadIdx.x & 63, w = threadIdx.x >> 6;
    int wm = (w >> 1) * 64, wn = (w & 1) * 64;
#pragma unroll
    for (int mt = 0; mt < 4; ++mt)
#pragma unroll
        for (int reg = 0; reg < 4; ++reg) {
            int row = m0 + wm + mt * 16 + (l >> 4) * 4 + reg;
            if (row >= NR) continue;
#pragma unroll
            for (int nt = 0; nt < 4; ++nt) {
                int col = n0 + wn + nt * 16 + (l & 15);
                outf[(size_t)row * DD + col] = acc[mt][nt][reg] + b2[col] + hbuf[(size_t)row * DD + col];
            }
        }
}

// ---------------- K11: pooled readout ---------------------------------------
__global__ void k_pool(const float* __restrict__ rowout, const int* __restrict__ starts,
                       float* __restrict__ out)
{
    int b = blockIdx.x; int d = threadIdx.x;
    int start = starts[b];
    int N = starts[b + 1] - start;
    if (N > MAXN) N = MAXN;
    float s = 0.f;
    for (int n = 0; n < N; ++n) s += rowout[(size_t)(start + n) * DD + d];
    s += (float)(MAXN - N) * rowout[(size_t)(NTOT + b) * DD + d];
    out[(size_t)b * DD + d] = s * (1.f / 512.f);
}

extern "C" void kernel_launch(void* const* d_in, const int* in_sizes, int n_in,
                              void* d_out, int out_size, void* d_ws, size_t ws_size,
                              hipStream_t stream) {
    const float* x   = (const float*)d_in[0];
    const int*   ind = (const int*)d_in[1];
    const float* Wq  = (const float*)d_in[2];
    const float* Wk  = (const float*)d_in[3];
    const float* Wv  = (const float*)d_in[4];
    const float* Wo  = (const float*)d_in[5];
    const float* bq  = (const float*)d_in[6];
    const float* bk  = (const float*)d_in[7];
    const float* bv  = (const float*)d_in[8];
    const float* bo  = (const float*)d_in[9];
    const float* g1  = (const float*)d_in[10];
    const float* be1 = (const float*)d_in[11];
    const float* W1  = (const float*)d_in[12];
    const float* b1  = (const float*)d_in[13];
    const float* W2  = (const float*)d_in[14];
    const float* b2  = (const float*)d_in[15];
    const float* g2  = (const float*)d_in[16];
    const float* be2 = (const float*)d_in[17];
    float* out = (float*)d_out;
    (void)in_sizes; (void)n_in; (void)out_size;

    char* ws = (char*)d_ws;
    const size_t rb2  = (size_t)NR * DD * sizeof(u16);    // 13.1 MB
    const size_t rb4  = (size_t)NR * DD * sizeof(float);  // 26.3 MB
    const size_t ffb  = (size_t)NR * FF * sizeof(u16);    // 52.5 MB
    const size_t vtb1 = (size_t)DD * NK * sizeof(u16);    // per-head vt: 16.8 MB
    const size_t wq_b = (size_t)HK * DD * sizeof(u16);
    const size_t w1_b = (size_t)FF * DD * sizeof(u16);
    const size_t rmb  = (size_t)NTOT * sizeof(int);
    const size_t fixed = 512 + rmb + 2 * rb4 + 2 * rb2 + 4 * wq_b + 2 * w1_b;
    const size_t per_g = 2 * rb2 + vtb1;                  // q + k + vt per head

    int G = 8;   // largest head-group whose footprint fits
    for (;;) {
        size_t need = fixed + (size_t)G * per_g + ((2 * (size_t)G * rb2 >= ffb) ? 0 : ffb);
        if (need <= ws_size || G == 1) break;
        G >>= 1;
    }

    size_t off = 0;
    int* starts = (int*)ws;              off += 512;
    int* rmap   = (int*)(ws + off);      off += rmb;
    u16* q   = (u16*)(ws + off);         off += (size_t)G * rb2;
    u16* k   = (u16*)(ws + off);         off += (size_t)G * rb2;
    u16* vt  = (u16*)(ws + off);         off += (size_t)G * vtb1;
    float* acc  = (float*)(ws + off);    off += rb4;
    float* hbuf = (float*)(ws + off);    off += rb4;
    u16* x16 = (u16*)(ws + off);         off += rb2;
    u16* h16 = (u16*)(ws + off);         off += rb2;
    u16* WqT = (u16*)(ws + off);         off += wq_b;
    u16* WkT = (u16*)(ws + off);         off += wq_b;
    u16* WvT = (u16*)(ws + off);         off += wq_b;
    u16* WoT = (u16*)(ws + off);         off += wq_b;
    u16* W1T = (u16*)(ws + off);         off += w1_b;
    u16* W2T = (u16*)(ws + off);         off += w1_b;
    u16* ff16 = (2 * (size_t)G * rb2 >= ffb) ? q : (u16*)(ws + off);  // alias q∪k after attn
    u16* o = q;   // alias: each attn wg reads only its own q rows before writing o

    hipLaunchKernelGGL(k_starts,   dim3(1),    dim3(128), 0, stream, ind, starts);
    hipLaunchKernelGGL(k_rowmap,   dim3(100),  dim3(256), 0, stream, starts, rmap);
    hipLaunchKernelGGL(k_cast_x,   dim3(NR),   dim3(256), 0, stream, x, x16);
    hipLaunchKernelGGL(k_transp,   dim3(2048), dim3(256), 0, stream, Wq, WqT, 8, HK);
    hipLaunchKernelGGL(k_transp,   dim3(2048), dim3(256), 0, stream, Wk, WkT, 8, HK);
    hipLaunchKernelGGL(k_transp,   dim3(2048), dim3(256), 0, stream, Wv, WvT, 8, HK);
    hipLaunchKernelGGL(k_transp,   dim3(2048), dim3(256), 0, stream, Wo, WoT, 11, DD);
    hipLaunchKernelGGL(k_transp,   dim3(1024), dim3(256), 0, stream, W1, W1T, 8, FF);
    hipLaunchKernelGGL(k_transp,   dim3(1024), dim3(256), 0, stream, W2, W2T, 10, DD);
    hipLaunchKernelGGL(k_init_acc, dim3(NR),   dim3(256), 0, stream, x, bo, acc);
    for (int h0 = 0; h0 < HH; h0 += G) {
        hipLaunchKernelGGL(k_qkv_mfma,  dim3(MT, 2 * G, 3), dim3(256), 0, stream,
                           x16, WqT, WkT, WvT, bq, bk, bv, q, k, vt, rmap, G, h0);
        hipLaunchKernelGGL(k_attn_mfma, dim3(BB * G, QT),   dim3(256), 0, stream,
                           q, k, vt, o, starts, bv, G, h0);
        hipLaunchKernelGGL(k_proj_mfma, dim3(MT, 2),        dim3(256), 0, stream,
                           o, WoT, acc, G, h0);
    }
    hipLaunchKernelGGL(k_ln,        dim3(NR / 4), dim3(256), 0, stream, acc, g1, be1, hbuf, h16);
    hipLaunchKernelGGL(k_ffn1_mfma, dim3(MT, 8),  dim3(256), 0, stream, h16, W1T, b1, ff16);
    hipLaunchKernelGGL(k_ffn2_mfma, dim3(MT, 2),  dim3(256), 0, stream, ff16, W2T, b2, hbuf, acc);
    hipLaunchKernelGGL(k_ln,        dim3(NR / 4), dim3(256), 0, stream, acc, g2, be2, acc, (u16*)nullptr);
    hipLaunchKernelGGL(k_pool,      dim3(BB),     dim3(256), 0, stream, acc, starts, out);
}